// Round 6
// baseline (1822.645 us; speedup 1.0000x reference)
//
#include <hip/hip_runtime.h>

typedef __attribute__((ext_vector_type(8))) _Float16 f16x8;
typedef __attribute__((ext_vector_type(16))) float f32x16;

#define B_    8
#define LSEQ  2048
#define DIM   1024

// fragment images (fp16), built by prepass:
//  F (dual K/Q use): [m][b][t32(64)][dkc(64)][lane(64)][8]  row-major frags
//  V (transposed):   [m][b][dt(32)][kv(128)][lane(64)][8]   col-major frags
#define FMAT_US ((size_t)LSEQ * DIM)          // 2M halfwords per (m,b)
#define WS_NEED ((size_t)4 * 16 * FMAT_US)    // 128 MB total (F + V)

static __device__ __forceinline__ unsigned pk2(float a, float b) {
    return __builtin_bit_cast(unsigned, __builtin_amdgcn_cvt_pkrtz(a, b));
}
static __device__ __forceinline__ f32x16 mm(f16x8 a, f16x8 b, f32x16 c) {
    return __builtin_amdgcn_mfma_f32_32x32x16_f16(a, b, c, 0, 0, 0);
}
#define LGKM0() asm volatile("s_waitcnt lgkmcnt(0)" ::: "memory")
#define BAR()   do { asm volatile("" ::: "memory"); __builtin_amdgcn_s_barrier(); \
                     asm volatile("" ::: "memory"); } while (0)

// ============ prepass: fp32 -> fp16 fragment images (fused K+V) ============
__global__ __launch_bounds__(256)
void prepass(const float* __restrict__ Sp, const float* __restrict__ Dp,
             unsigned short* __restrict__ Fimg, unsigned short* __restrict__ Vimg)
{
    const int blk   = blockIdx.x;          // 2*8*16*8 = 2048
    const int dt128 = blk & 7;             // d-group of 128
    const int kt128 = (blk >> 3) & 15;     // k-group of 128
    const int b     = (blk >> 7) & 7;
    const int m     = blk >> 10;
    const float* src = (m ? Dp : Sp) + ((size_t)b * LSEQ + kt128 * 128) * DIM + dt128 * 128;
    unsigned short* fb = Fimg + (size_t)(m * 8 + b) * FMAT_US;
    unsigned short* vb = Vimg + (size_t)(m * 8 + b) * FMAT_US;

    __shared__ float tile[128][132];       // 66 KB, row stride 528B (16B aligned)
    const int t = threadIdx.x;

    #pragma unroll
    for (int i = 0; i < 16; ++i) {
        const int idx = t + i * 256;       // 4096 float4
        const int r = idx >> 5, c4 = idx & 31;
        const float4 v = *(const float4*)(src + (size_t)r * DIM + c4 * 4);
        *(float4*)&tile[r][c4 * 4] = v;
    }
    __syncthreads();

    // K-frags: lane l holds M[kt*32 + (l&31)][dkc*16 + (l>>5)*8 .. +8]
    // 32 frags x 64 lanes = 2048 entries -> 8 iters of 256 threads
    #pragma unroll
    for (int i = 0; i < 8; ++i) {
        const int idx = t + i * 256;
        const int fr = idx >> 6, l = idx & 63;     // fr 0..31
        const int t32loc = fr >> 3, f = fr & 7;
        const int row = t32loc * 32 + (l & 31);
        const int col = f * 16 + (l >> 5) * 8;
        const float* sp = &tile[row][col];
        uint4 o;
        o.x = pk2(sp[0], sp[1]); o.y = pk2(sp[2], sp[3]);
        o.z = pk2(sp[4], sp[5]); o.w = pk2(sp[6], sp[7]);
        const size_t kt = kt128 * 4 + t32loc, dkc = dt128 * 8 + f;
        *(uint4*)(fb + ((kt * 64 + dkc) * 64 + l) * 8) = o;
    }
    // V-frags: lane l holds M[kv*16 + (l>>5)*8 .. +8][dt*32 + (l&31)]  (transposed)
    #pragma unroll
    for (int i = 0; i < 8; ++i) {
        const int idx = t + i * 256;
        const int fr = idx >> 6, l = idx & 63;     // fr 0..31
        const int dtloc = fr >> 3, f = fr & 7;
        const int col = dtloc * 32 + (l & 31);
        const int row = f * 16 + (l >> 5) * 8;
        uint4 o;
        o.x = pk2(tile[row + 0][col], tile[row + 1][col]);
        o.y = pk2(tile[row + 2][col], tile[row + 3][col]);
        o.z = pk2(tile[row + 4][col], tile[row + 5][col]);
        o.w = pk2(tile[row + 6][col], tile[row + 7][col]);
        const size_t dt = dt128 * 4 + dtloc, kv = kt128 * 8 + f;
        *(uint4*)(vb + ((dt * 128 + kv) * 64 + l) * 8) = o;
    }
}

// ============ main: VMEM-direct operands, LDS only for P + reductions ============
__global__ __launch_bounds__(512, 2)
void coattn_main(const float* __restrict__ Sp, const float* __restrict__ Dp,
                 float* __restrict__ outp,
                 const unsigned short* __restrict__ Fimg,
                 const unsigned short* __restrict__ Vimg)
{
    const int s   = blockIdx.x;            // 512 blocks; XCD = b (both dirs of b colocate)
    const int qb  = (s >> 3) & 31;
    const int dir = s >> 8;
    const int b   = s & 7;
    const int mat_k = dir;                 // dir0: K=S(0); dir1: K=D(1)
    const int mat_q = 1 - dir;

    const float* Qg = (dir ? Sp : Dp) + (size_t)b * LSEQ * DIM;   // residual (fp32)
    float* Og = outp + (size_t)dir * ((size_t)B_ * LSEQ * DIM) + (size_t)b * LSEQ * DIM;
    const int q0 = qb * 64;

    const f16x8* KF = (const f16x8*)(Fimg + (size_t)(mat_k * 8 + b) * FMAT_US);
    const f16x8* QF = (const f16x8*)(Fimg + (size_t)(mat_q * 8 + b) * FMAT_US);
    const f16x8* VF = (const f16x8*)(Vimg + (size_t)(mat_k * 8 + b) * FMAT_US);

    __shared__ unsigned short Plds[64 * 256];   // 32 KB
    __shared__ float redmax[2][4][32];
    __shared__ float redsum[2][4][32];
    __shared__ float alf[64];

    const int t    = threadIdx.x;
    const int lane = t & 63;
    const int w    = t >> 6;
    const int l31  = lane & 31;
    const int hi   = lane >> 5;
    const int ks4  = w & 3;                 // QK: k-quarter (64 k each)
    const int qh   = w >> 2;                // q half
    const int dq   = w & 3;                 // PV: d-column slot

    const int qrow = qh * 32 + l31;
    const int qswz = (qrow & 7) << 3;
    const int qt   = qb * 2 + qh;           // global 32-row Q tile index

    f32x16 O[8];
    #pragma unroll
    for (int i = 0; i < 8; ++i)
        #pragma unroll
        for (int r = 0; r < 16; ++r) O[i][r] = 0.0f;

    float m_run = -INFINITY, l_run = 0.0f;

    const f16x8* qp = QF + ((size_t)qt * 64) * 64 + lane;

    #pragma unroll 1
    for (int kb = 0; kb < 8; ++kb) {
        const int kt0 = kb * 8 + ks4 * 2;
        const f16x8* kp0 = KF + ((size_t)kt0 * 64) * 64 + lane;
        const f16x8* kp1 = KF + ((size_t)(kt0 + 1) * 64) * 64 + lane;

        // ---- QK^T: 64 d-steps, depth-3 register pipeline, zero barriers ----
        f32x16 C0, C1;
        #pragma unroll
        for (int r = 0; r < 16; ++r) { C0[r] = 0.0f; C1[r] = 0.0f; }

        f16x8 kr[8], qr[4];
        #pragma unroll
        for (int ss = 0; ss < 3; ++ss) {
            kr[(2 * ss) & 7]     = kp0[(size_t)ss * 64];
            kr[(2 * ss + 1) & 7] = kp1[(size_t)ss * 64];
            qr[ss & 3]           = qp[(size_t)ss * 64];
        }
        #pragma unroll
        for (int st = 0; st < 64; ++st) {
            if (st + 3 < 64) {
                const int sp = st + 3;
                kr[(2 * sp) & 7]     = kp0[(size_t)sp * 64];
                kr[(2 * sp + 1) & 7] = kp1[(size_t)sp * 64];
                qr[sp & 3]           = qp[(size_t)sp * 64];
            }
            C0 = mm(kr[(2 * st) & 7],     qr[st & 3], C0);
            C1 = mm(kr[(2 * st + 1) & 7], qr[st & 3], C1);
        }

        // ---- online softmax over this 256-k block ----
        // lane holds C{j}[r] at (k = 64*ks4 + 32*j + crow(r,hi), q = 32*qh + l31)
        float rm = -INFINITY;
        #pragma unroll
        for (int r = 0; r < 16; ++r) { rm = fmaxf(rm, C0[r]); rm = fmaxf(rm, C1[r]); }
        rm = fmaxf(rm, __shfl_xor(rm, 32));
        if (lane < 32) redmax[qh][ks4][l31] = rm;
        LGKM0();
        BAR();

        // prime PV V-pipeline (latency hides under exp)
        const f16x8* vptr = VF + ((size_t)(dq * 128 + kb * 16)) * 64 + lane;
        f16x8 vring[8];
        #pragma unroll
        for (int i = 0; i < 6; ++i)
            vring[i] = vptr[(size_t)(i >> 4) * 32768 + (i & 15) * 64];

        const float bm = fmaxf(fmaxf(redmax[qh][0][l31], redmax[qh][1][l31]),
                               fmaxf(redmax[qh][2][l31], redmax[qh][3][l31]));
        const float mn = fmaxf(m_run, bm);
        const float al = __expf(m_run - mn);
        float p0[16], p1[16];
        float ps = 0.0f;
        #pragma unroll
        for (int r = 0; r < 16; ++r) {
            p0[r] = __expf(C0[r] - mn); ps += p0[r];
            p1[r] = __expf(C1[r] - mn); ps += p1[r];
        }
        ps += __shfl_xor(ps, 32);
        if (lane < 32) {
            redsum[qh][ks4][l31] = ps;
            if (ks4 == 0) alf[qh * 32 + l31] = al;
        }
        // P (fp16) -> LDS [q][256k], swizzled; b64 packs of 4 contiguous crow
        #pragma unroll
        for (int j = 0; j < 2; ++j)
            #pragma unroll
            for (int g = 0; g < 4; ++g) {
                const int kk0 = 64 * ks4 + 32 * j + 8 * g + 4 * hi;
                const float* pj = j ? p1 : p0;
                uint2 v;
                v.x = pk2(pj[4 * g + 0], pj[4 * g + 1]);
                v.y = pk2(pj[4 * g + 2], pj[4 * g + 3]);
                *(uint2*)&Plds[qrow * 256 + (kk0 ^ qswz)] = v;
            }
        LGKM0();
        BAR();

        const float bs = redsum[qh][0][l31] + redsum[qh][1][l31] +
                         redsum[qh][2][l31] + redsum[qh][3][l31];
        l_run = l_run * al + bs;
        m_run = mn;

        float alr[16];
        #pragma unroll
        for (int r = 0; r < 16; ++r)
            alr[r] = alf[qh * 32 + (r & 3) + 8 * (r >> 2) + 4 * hi];
        #pragma unroll
        for (int i = 0; i < 8; ++i)
            #pragma unroll
            for (int r = 0; r < 16; ++r) O[i][r] *= alr[r];

        f16x8 pa[16];
        #pragma unroll
        for (int kc = 0; kc < 16; ++kc)
            pa[kc] = *(const f16x8*)&Plds[qrow * 256 + ((kc * 16 + hi * 8) ^ qswz)];

        // ---- PV: 128 steps (8 bands x 16 kc), depth-6 register pipeline ----
        #pragma unroll
        for (int st = 0; st < 128; ++st) {
            if (st + 6 < 128) {
                const int sp = st + 6;
                vring[sp & 7] = vptr[(size_t)(sp >> 4) * 32768 + (sp & 15) * 64];
            }
            O[st >> 4] = mm(pa[st & 15], vring[st & 7], O[st >> 4]);
        }
    }

    // ---- epilogue: out = residual(Q) + O / l ----
    __syncthreads();
    if (lane < 32 && ks4 == 0) alf[qh * 32 + l31] = 1.0f / l_run;
    __syncthreads();
    #pragma unroll
    for (int r = 0; r < 16; ++r) {
        const int qr2 = qh * 32 + (r & 3) + 8 * (r >> 2) + 4 * hi;
        const float il = alf[qr2];
        const size_t rowoff = (size_t)(q0 + qr2) * DIM;
        #pragma unroll
        for (int band = 0; band < 8; ++band) {
            const int dcol = band * 128 + dq * 32 + l31;
            Og[rowoff + dcol] = Qg[rowoff + dcol] + O[band][r] * il;
        }
    }
}

// ============ fallback (round-2 kernel, verbatim — used if ws too small) ============
#define KBLK  128
#define NKBF  16
#define NDC   8
#define NBAND 8

__global__ __launch_bounds__(512, 2)
void coattn_fb(const float* __restrict__ Sp, const float* __restrict__ Dp,
               float* __restrict__ outp)
{
    const int s   = blockIdx.x;
    const int g   = (s & 7) | ((s >> 8) << 3);
    const int qb  = (s >> 3) & 31;
    const int dir = g >> 3;
    const int b   = g & 7;

    const float* Qg = (dir ? Sp : Dp) + (size_t)b * LSEQ * DIM;
    const float* Kg = (dir ? Dp : Sp) + (size_t)b * LSEQ * DIM;
    float* Og = outp + (size_t)dir * ((size_t)B_ * LSEQ * DIM) + (size_t)b * LSEQ * DIM;
    const int q0 = qb * 64;

    __shared__ unsigned short Klds[KBLK * 128];
    __shared__ unsigned short Qlds[64 * 128];
    __shared__ unsigned short Plds[64 * KBLK];
    __shared__ unsigned short Vlds[128 * KBLK];
    __shared__ float redmax[2][4][32];
    __shared__ float redsum[2][4][32];
    __shared__ float alf[64];

    const int t    = threadIdx.x;
    const int lane = t & 63;
    const int w    = t >> 6;
    const int l31  = lane & 31;
    const int hi   = lane >> 5;
    const int ksub = w & 3;
    const int qh   = w >> 2;

    f32x16 O[NBAND];
    #pragma unroll
    for (int i = 0; i < NBAND; ++i)
        #pragma unroll
        for (int r = 0; r < 16; ++r) O[i][r] = 0.0f;

    float m_run = -INFINITY, l_run = 0.0f;

    const int srow = t >> 4;
    const int fcol = (t & 15) << 2;
    const int vmm  = t & 31;
    const int vkp0 = t >> 5;

    const int krow = ksub * 32 + l31;
    const int qrow = qh * 32 + l31;

    for (int kb = 0; kb < NKBF; ++kb) {
        const int k0g = kb * KBLK;
        f32x16 C;
        #pragma unroll
        for (int r = 0; r < 16; ++r) C[r] = 0.0f;

        float4 kreg[8], qreg[4];
        #pragma unroll
        for (int pass = 0; pass < 4; ++pass)
            #pragma unroll
            for (int h = 0; h < 2; ++h)
                kreg[pass * 2 + h] = *(const float4*)(Kg + (size_t)(k0g + pass * 32 + srow) * DIM + fcol + h * 64);
        #pragma unroll
        for (int pass = 0; pass < 2; ++pass)
            #pragma unroll
            for (int h = 0; h < 2; ++h)
                qreg[pass * 2 + h] = *(const float4*)(Qg + (size_t)(q0 + pass * 32 + srow) * DIM + fcol + h * 64);

        #pragma unroll 1
        for (int dc = 0; dc < NDC; ++dc) {
            __syncthreads();
            #pragma unroll
            for (int pass = 0; pass < 4; ++pass)
                #pragma unroll
                for (int h = 0; h < 2; ++h) {
                    const int row = pass * 32 + srow;
                    const int d   = fcol + h * 64;
                    const float4 v = kreg[pass * 2 + h];
                    *(uint2*)&Klds[row * 128 + (d ^ ((row & 7) << 3))] =
                        make_uint2(pk2(v.x, v.y), pk2(v.z, v.w));
                }
            #pragma unroll
            for (int pass = 0; pass < 2; ++pass)
                #pragma unroll
                for (int h = 0; h < 2; ++h) {
                    const int row = pass * 32 + srow;
                    const int d   = fcol + h * 64;
                    const float4 v = qreg[pass * 2 + h];
                    *(uint2*)&Qlds[row * 128 + (d ^ ((row & 7) << 3))] =
                        make_uint2(pk2(v.x, v.y), pk2(v.z, v.w));
                }
            __syncthreads();
            if (dc + 1 < NDC) {
                const int dbase = (dc + 1) * 128;
                #pragma unroll
                for (int pass = 0; pass < 4; ++pass)
                    #pragma unroll
                    for (int h = 0; h < 2; ++h)
                        kreg[pass * 2 + h] = *(const float4*)(Kg + (size_t)(k0g + pass * 32 + srow) * DIM + dbase + fcol + h * 64);
                #pragma unroll
                for (int pass = 0; pass < 2; ++pass)
                    #pragma unroll
                    for (int h = 0; h < 2; ++h)
                        qreg[pass * 2 + h] = *(const float4*)(Qg + (size_t)(q0 + pass * 32 + srow) * DIM + dbase + fcol + h * 64);
            }
            #pragma unroll
            for (int kc = 0; kc < 8; ++kc) {
                const int d0 = kc * 16 + hi * 8;
                f16x8 a  = *(const f16x8*)&Klds[krow * 128 + (d0 ^ ((krow & 7) << 3))];
                f16x8 bq = *(const f16x8*)&Qlds[qrow * 128 + (d0 ^ ((qrow & 7) << 3))];
                C = __builtin_amdgcn_mfma_f32_32x32x16_f16(a, bq, C, 0, 0, 0);
            }
        }

        float rm = -INFINITY;
        #pragma unroll
        for (int r = 0; r < 16; ++r) rm = fmaxf(rm, C[r]);
        rm = fmaxf(rm, __shfl_xor(rm, 32));
        if (lane < 32) redmax[qh][ksub][l31] = rm;
        __syncthreads();

        const float bm = fmaxf(fmaxf(redmax[qh][0][l31], redmax[qh][1][l31]),
                               fmaxf(redmax[qh][2][l31], redmax[qh][3][l31]));
        const float mn = fmaxf(m_run, bm);
        const float al = __expf(m_run - mn);
        float p[16];
        float ps = 0.0f;
        #pragma unroll
        for (int r = 0; r < 16; ++r) { p[r] = __expf(C[r] - mn); ps += p[r]; }
        ps += __shfl_xor(ps, 32);
        if (lane < 32) {
            redsum[qh][ksub][l31] = ps;
            if (ksub == 0) alf[qh * 32 + l31] = al;
        }
        {
            #pragma unroll
            for (int rp = 0; rp < 8; ++rp) {
                const int r  = rp * 2;
                const int kk = ksub * 32 + (r & 3) + 8 * (r >> 2) + 4 * hi;
                *(unsigned*)&Plds[qrow * KBLK + (kk ^ ((qrow & 7) << 3))] = pk2(p[r], p[r + 1]);
            }
        }
        __syncthreads();

        const float bs = redsum[qh][0][l31] + redsum[qh][1][l31] +
                         redsum[qh][2][l31] + redsum[qh][3][l31];
        l_run = l_run * al + bs;
        m_run = mn;

        float alr[16];
        #pragma unroll
        for (int r = 0; r < 16; ++r)
            alr[r] = alf[qh * 32 + (r & 3) + 8 * (r >> 2) + 4 * hi];
        #pragma unroll
        for (int i = 0; i < NBAND; ++i)
            #pragma unroll
            for (int r = 0; r < 16; ++r) O[i][r] *= alr[r];

        f16x8 pa[8];
        #pragma unroll
        for (int kc = 0; kc < 8; ++kc) {
            const int kk0 = kc * 16 + hi * 8;
            pa[kc] = *(const f16x8*)&Plds[qrow * KBLK + (kk0 ^ ((qrow & 7) << 3))];
        }

        float4 v0s[4], v1s[4];
        #pragma unroll
        for (int pass = 0; pass < 4; ++pass) {
            const int kp = pass * 16 + vkp0;
            v0s[pass] = *(const float4*)(Kg + (size_t)(k0g + 2 * kp) * DIM + vmm * 4);
            v1s[pass] = *(const float4*)(Kg + (size_t)(k0g + 2 * kp + 1) * DIM + vmm * 4);
        }

        #pragma unroll
        for (int band = 0; band < NBAND; ++band) {
            __syncthreads();
            #pragma unroll
            for (int pass = 0; pass < 4; ++pass) {
                const int kp = pass * 16 + vkp0;
                const float* a0 = (const float*)&v0s[pass];
                const float* a1 = (const float*)&v1s[pass];
                #pragma unroll
                for (int j = 0; j < 4; ++j) {
                    const int dclw = vmm * 4 + j;
                    *(unsigned*)&Vlds[dclw * KBLK + ((2 * kp) ^ ((dclw & 7) << 3))] = pk2(a0[j], a1[j]);
                }
            }
            __syncthreads();
            if (band + 1 < NBAND) {
                const int cb = (band + 1) * 128;
                #pragma unroll
                for (int pass = 0; pass < 4; ++pass) {
                    const int kp = pass * 16 + vkp0;
                    v0s[pass] = *(const float4*)(Kg + (size_t)(k0g + 2 * kp) * DIM + cb + vmm * 4);
                    v1s[pass] = *(const float4*)(Kg + (size_t)(k0g + 2 * kp + 1) * DIM + cb + vmm * 4);
                }
            }
            const int dclr = ksub * 32 + l31;
            const int sw  = (dclr & 7) << 3;
            #pragma unroll
            for (int kc = 0; kc < 8; ++kc) {
                const int kk0 = kc * 16 + hi * 8;
                f16x8 vb = *(const f16x8*)&Vlds[dclr * KBLK + (kk0 ^ sw)];
                O[band] = __builtin_amdgcn_mfma_f32_32x32x16_f16(pa[kc], vb, O[band], 0, 0, 0);
            }
        }
    }

    if (lane < 32 && ksub == 0) alf[qh * 32 + l31] = 1.0f / l_run;
    __syncthreads();
    #pragma unroll
    for (int r = 0; r < 16; ++r) {
        const int qr = qh * 32 + (r & 3) + 8 * (r >> 2) + 4 * hi;
        const float il = alf[qr];
        const size_t rowoff = (size_t)(q0 + qr) * DIM;
        #pragma unroll
        for (int band = 0; band < NBAND; ++band) {
            const int dcol = band * 128 + ksub * 32 + l31;
            Og[rowoff + dcol] = Qg[rowoff + dcol] + O[band][r] * il;
        }
    }
}

extern "C" void kernel_launch(void* const* d_in, const int* in_sizes, int n_in,
                              void* d_out, int out_size, void* d_ws, size_t ws_size,
                              hipStream_t stream) {
    const float* S = (const float*)d_in[0];
    const float* D = (const float*)d_in[1];
    float* out = (float*)d_out;
    if (ws_size >= WS_NEED) {
        unsigned short* Fimg = (unsigned short*)d_ws;
        unsigned short* Vimg = Fimg + 16 * FMAT_US;
        prepass<<<dim3(2048, 1, 1), dim3(256, 1, 1), 0, stream>>>(S, D, Fimg, Vimg);
        coattn_main<<<dim3(512, 1, 1), dim3(512, 1, 1), 0, stream>>>(S, D, out, Fimg, Vimg);
    } else {
        coattn_fb<<<dim3(512, 1, 1), dim3(512, 1, 1), 0, stream>>>(S, D, out);
    }
}

// Round 7
// 869.465 us; speedup vs baseline: 2.0963x; 2.0963x over previous
//
#include <hip/hip_runtime.h>

typedef __attribute__((ext_vector_type(8))) _Float16 f16x8;
typedef __attribute__((ext_vector_type(16))) float f32x16;

#define B_    8
#define LSEQ  2048
#define DIM   1024
#define QBLK  64
#define KBLK  128
#define NKB   (LSEQ / KBLK)   // 16
#define NBAND 8

// K/V image geometry: 32KB tiles (128x128 fp16, swizzle baked in)
#define TILE_US   16384        // ushorts per tile
#define KIMG_US   ((size_t)2 * 8 * 16 * 8 * TILE_US)   // 64 MB
#define WS_NEED   ((size_t)2 * KIMG_US * 2)            // 128 MB

static __device__ __forceinline__ unsigned pk2(float a, float b) {
    return __builtin_bit_cast(unsigned, __builtin_amdgcn_cvt_pkrtz(a, b));
}

#define VMCNT(n) asm volatile("s_waitcnt vmcnt(" #n ")" ::: "memory")
#define LGKM0()  asm volatile("s_waitcnt lgkmcnt(0)" ::: "memory")
#define BAR()    do { asm volatile("" ::: "memory"); __builtin_amdgcn_s_barrier(); \
                      asm volatile("" ::: "memory"); } while (0)

static __device__ __forceinline__ int s3(int x) { return x >= 3 ? x - 3 : x; }

static __device__ __forceinline__ void gll16(const void* g, void* l) {
    __builtin_amdgcn_global_load_lds(
        (const __attribute__((address_space(1))) void*)g,
        (__attribute__((address_space(3))) void*)l, 16, 0, 0);
}

// 32KB tile: 8 waves x 4 ops x 1KB ; 16KB tile: 8 waves x 2 ops x 1KB
static __device__ __forceinline__ void issue32(const unsigned short* gt, unsigned short* lb, int w, int lane) {
    #pragma unroll
    for (int j = 0; j < 4; ++j) {
        const int off = (w * 4 + j) * 1024;
        gll16((const char*)gt + off + lane * 16, (char*)lb + off);
    }
}
static __device__ __forceinline__ void issue16(const unsigned short* gt, unsigned short* lb, int w, int lane) {
    #pragma unroll
    for (int j = 0; j < 2; ++j) {
        const int off = (w * 2 + j) * 1024;
        gll16((const char*)gt + off + lane * 16, (char*)lb + off);
    }
}

// ============ prepass: fp32 -> fp16 swizzled LDS-image tiles (R3/R4, proven) ============
__global__ __launch_bounds__(256)
void prepass(const float* __restrict__ Sp, const float* __restrict__ Dp,
             unsigned short* __restrict__ Kimg, unsigned short* __restrict__ Vimg)
{
    const int blk = blockIdx.x;            // 2*8*16*8 = 2048
    const int dc = blk & 7;
    const int kb = (blk >> 3) & 15;
    const int b  = (blk >> 7) & 7;
    const int m  = blk >> 10;
    const float* src = (m ? Dp : Sp) + ((size_t)b * LSEQ + kb * 128) * DIM + dc * 128;
    unsigned short* kt = Kimg + (size_t)((((m * 8 + b) * 16 + kb) * 8) + dc) * TILE_US;
    unsigned short* vt = Vimg + (size_t)((((m * 8 + b) * 8 + dc) * 16) + kb) * TILE_US;

    __shared__ unsigned short tile[128 * 132];
    const int t = threadIdx.x;

    #pragma unroll
    for (int i = 0; i < 16; ++i) {
        const int idx = t + i * 256;
        const int r = idx >> 5;
        const int c4 = (idx & 31) << 2;
        const float4 v = *(const float4*)(src + (size_t)r * DIM + c4);
        const unsigned lo = pk2(v.x, v.y), hi2 = pk2(v.z, v.w);
        *(uint2*)(kt + r * 128 + (c4 ^ ((r & 7) << 3))) = make_uint2(lo, hi2);
        *(uint2*)(&tile[r * 132 + c4]) = make_uint2(lo, hi2);
    }
    __syncthreads();
    #pragma unroll
    for (int i = 0; i < 32; ++i) {
        const int widx = t + i * 256;
        const int dcl = widx >> 6;
        const int wk  = widx & 63;
        const unsigned a  = tile[(wk * 2) * 132 + dcl];
        const unsigned bb = tile[(wk * 2 + 1) * 132 + dcl];
        ((unsigned*)vt)[dcl * 64 + (wk ^ ((dcl & 7) << 2))] = a | (bb << 16);
    }
}

// ============ main: R4 ring + corrected sync protocol ============
// per phase p: VMCNT(N) [item p complete, own ops]; BAR [all waves' item p complete,
// all readers of slot(p+2) past]; issue item p+2; MFMA item p.  2-phase latency cover.
__global__ __launch_bounds__(512, 2)
void coattn_main(const float* __restrict__ Sp, const float* __restrict__ Dp,
                 float* __restrict__ outp,
                 const unsigned short* __restrict__ Kimg,
                 const unsigned short* __restrict__ Vimg)
{
    const int s   = blockIdx.x;
    const int g   = (s & 7) | ((s >> 8) << 3);
    const int qb  = (s >> 3) & 31;
    const int dir = g >> 3;
    const int b   = g & 7;
    const int mat_k = dir;
    const int mat_q = 1 - dir;

    const float* Qg = (dir ? Sp : Dp) + (size_t)b * LSEQ * DIM;
    float* Og = outp + (size_t)dir * ((size_t)B_ * LSEQ * DIM) + (size_t)b * LSEQ * DIM;
    const int q0 = qb * QBLK;

    const unsigned short* kbase = Kimg + (size_t)(mat_k * 8 + b) * 16 * 8 * TILE_US;
    const unsigned short* qbase = Kimg + (size_t)(mat_q * 8 + b) * 16 * 8 * TILE_US
                                + (size_t)(qb >> 1) * 8 * TILE_US + (size_t)(qb & 1) * 8192;
    const unsigned short* vbase = Vimg + (size_t)(mat_k * 8 + b) * 8 * 16 * TILE_US;

    __shared__ unsigned short Rr[3][16384];   // 96 KB: K-chunks / V-bands ring
    __shared__ unsigned short QR_[3][8192];   // 48 KB: Q-chunks ring (one slot aliased for P)
    __shared__ float redmax[2][4][32];
    __shared__ float redsum[2][4][32];
    __shared__ float alf[QBLK];

    const int t    = threadIdx.x;
    const int lane = t & 63;
    const int w    = t >> 6;
    const int l31  = lane & 31;
    const int hi   = lane >> 5;
    const int ksub = w & 3;
    const int qh   = w >> 2;

    const int krow = ksub * 32 + l31;
    const int qrow = qh * 32 + l31;
    const int kswz = (krow & 7) << 3;
    const int qswz = (qrow & 7) << 3;
    const int dcl  = ksub * 32 + l31;
    const int vswz = (dcl & 7) << 3;

    f32x16 O[NBAND];
    #pragma unroll
    for (int i = 0; i < NBAND; ++i)
        #pragma unroll
        for (int r = 0; r < 16; ++r) O[i][r] = 0.0f;

    float m_run = -INFINITY, l_run = 0.0f;

    #define QK_MMA(RS, QS)                                                        \
    do {                                                                          \
        const unsigned short* Kb = Rr[RS];                                        \
        const unsigned short* Qb = QR_[QS];                                       \
        __builtin_amdgcn_s_setprio(1);                                            \
        _Pragma("unroll")                                                         \
        for (int kc = 0; kc < 8; ++kc) {                                          \
            const int d0 = kc * 16 + hi * 8;                                      \
            f16x8 a  = *(const f16x8*)&Kb[krow * 128 + (d0 ^ kswz)];              \
            f16x8 bq = *(const f16x8*)&Qb[qrow * 128 + (d0 ^ qswz)];              \
            C = __builtin_amdgcn_mfma_f32_32x32x16_f16(a, bq, C, 0, 0, 0);        \
        }                                                                         \
        __builtin_amdgcn_s_setprio(0);                                            \
    } while (0)

    #define PV_MMA(BAND, RS)                                                      \
    do {                                                                          \
        const unsigned short* Vb = Rr[RS];                                        \
        __builtin_amdgcn_s_setprio(1);                                            \
        _Pragma("unroll")                                                         \
        for (int kc = 0; kc < 8; ++kc) {                                          \
            const int kk0 = kc * 16 + hi * 8;                                     \
            f16x8 vb = *(const f16x8*)&Vb[dcl * 128 + (kk0 ^ vswz)];              \
            O[BAND] = __builtin_amdgcn_mfma_f32_32x32x16_f16(pa[kc], vb, O[BAND], 0, 0, 0); \
        }                                                                         \
        __builtin_amdgcn_s_setprio(0);                                            \
    } while (0)

    // QK phase P (0..5): wait item P, issue item P+2 (KQ chunk P+2), compute chunk P
    #define QK_PHASE(P)                                                           \
    do {                                                                          \
        VMCNT(6); BAR();                                                          \
        issue32(kt + (P + 2) * TILE_US, Rr[s3(sb + ((P + 2) % 3))], w, lane);     \
        issue16(qbase + (P + 2) * TILE_US, QR_[s3(qsb + ((P + 2) % 3))], w, lane);\
        QK_MMA(s3(sb + (P % 3)), s3(qsb + (P % 3)));                              \
    } while (0)

    // PV phase for band V (0..5): wait item 8+V, issue V-band V+2, compute band V
    #define PV_PHASE(V)                                                           \
    do {                                                                          \
        VMCNT(4); BAR();                                                          \
        issue32(vbase + (size_t)((V + 2) * 16 + kb) * TILE_US,                    \
                Rr[s3(sb + ((V + 10) % 3))], w, lane);                            \
        PV_MMA(V, s3(sb + ((V + 8) % 3)));                                        \
    } while (0)

    // prologue: items 0,1 (KQ chunks 0,1) in flight; slots 0,1 (kb=0: sb=qsb=0)
    {
        const unsigned short* kt0 = kbase;
        issue32(kt0 + 0 * TILE_US, Rr[0], w, lane);
        issue16(qbase + 0 * TILE_US, QR_[0], w, lane);
        issue32(kt0 + 1 * TILE_US, Rr[1], w, lane);
        issue16(qbase + 1 * TILE_US, QR_[1], w, lane);
    }

    int sb = 0, qsb = 0;   // rotating ring bases: sb=(kb*16)%3, qsb=(kb*8)%3

    #pragma unroll 1
    for (int kb = 0; kb < NKB; ++kb) {
        const unsigned short* kt = kbase + (size_t)kb * 8 * TILE_US;

        f32x16 C;
        #pragma unroll
        for (int r = 0; r < 16; ++r) C[r] = 0.0f;

        // ---- QK phases 0..7 ----
        QK_PHASE(0); QK_PHASE(1); QK_PHASE(2);
        QK_PHASE(3); QK_PHASE(4); QK_PHASE(5);
        // phase 6: issue V0 (item 8)
        VMCNT(6); BAR();
        issue32(vbase + (size_t)(0 * 16 + kb) * TILE_US, Rr[s3(sb + 2)], w, lane);
        QK_MMA(s3(sb + 0), s3(qsb + 0));
        // phase 7: issue V1 (item 9); item 8 is V (4 ops) -> wait 4
        VMCNT(4); BAR();
        issue32(vbase + (size_t)(1 * 16 + kb) * TILE_US, Rr[s3(sb + 0)], w, lane);
        QK_MMA(s3(sb + 1), s3(qsb + 1));

        // ---- online softmax (lgkm-only barriers: V0/V1 DMA stays in flight) ----
        unsigned short* Plds = QR_[s3(qsb + 1)];   // slot untouched until next kb's phases 14/15

        float rm = -INFINITY;
        #pragma unroll
        for (int r = 0; r < 16; ++r) rm = fmaxf(rm, C[r]);
        rm = fmaxf(rm, __shfl_xor(rm, 32));
        if (lane < 32) redmax[qh][ksub][l31] = rm;
        LGKM0(); BAR();

        const float bm = fmaxf(fmaxf(redmax[qh][0][l31], redmax[qh][1][l31]),
                               fmaxf(redmax[qh][2][l31], redmax[qh][3][l31]));
        const float mn = fmaxf(m_run, bm);
        const float al = __expf(m_run - mn);
        float p[16];
        float ps = 0.0f;
        #pragma unroll
        for (int r = 0; r < 16; ++r) { p[r] = __expf(C[r] - mn); ps += p[r]; }
        ps += __shfl_xor(ps, 32);
        if (lane < 32) {
            redsum[qh][ksub][l31] = ps;
            if (ksub == 0) alf[qh * 32 + l31] = al;
        }
        {   // P (fp16) -> LDS [q][k]
            #pragma unroll
            for (int rp = 0; rp < 8; ++rp) {
                const int r  = rp * 2;
                const int kk = ksub * 32 + (r & 3) + 8 * (r >> 2) + 4 * hi;
                *(unsigned*)&Plds[qrow * KBLK + (kk ^ qswz)] = pk2(p[r], p[r + 1]);
            }
        }
        LGKM0(); BAR();

        const float bs = redsum[qh][0][l31] + redsum[qh][1][l31] +
                         redsum[qh][2][l31] + redsum[qh][3][l31];
        l_run = l_run * al + bs;
        m_run = mn;

        float alr[16];
        #pragma unroll
        for (int r = 0; r < 16; ++r)
            alr[r] = alf[qh * 32 + (r & 3) + 8 * (r >> 2) + 4 * hi];
        #pragma unroll
        for (int i = 0; i < NBAND; ++i)
            #pragma unroll
            for (int r = 0; r < 16; ++r) O[i][r] *= alr[r];

        f16x8 pa[8];
        #pragma unroll
        for (int kc = 0; kc < 8; ++kc) {
            const int kk0 = kc * 16 + hi * 8;
            pa[kc] = *(const f16x8*)&Plds[qrow * KBLK + (kk0 ^ qswz)];
        }

        // ---- PV phases 8..15 (bands 0..7) ----
        PV_PHASE(0); PV_PHASE(1); PV_PHASE(2);
        PV_PHASE(3); PV_PHASE(4); PV_PHASE(5);
        // phase 14 (band 6): issue next-kb KQ0 (item 16)
        VMCNT(4); BAR();
        if (kb + 1 < NKB) {
            const unsigned short* ktn = kbase + (size_t)(kb + 1) * 8 * TILE_US;
            issue32(ktn + 0 * TILE_US, Rr[s3(sb + 1)], w, lane);
            issue16(qbase + 0 * TILE_US, QR_[s3(qsb + 2)], w, lane);
        }
        PV_MMA(6, s3(sb + 2));
        // phase 15 (band 7): issue next-kb KQ1 (item 17); item 16 is KQ (6 ops)
        if (kb + 1 < NKB) {
            VMCNT(6); BAR();
            const unsigned short* ktn = kbase + (size_t)(kb + 1) * 8 * TILE_US;
            issue32(ktn + 1 * TILE_US, Rr[s3(sb + 2)], w, lane);
            issue16(qbase + 1 * TILE_US, QR_[qsb], w, lane);
        } else {
            VMCNT(0); BAR();
        }
        PV_MMA(7, sb);

        sb = s3(sb + 1);     // (kb+1)*16 % 3
        qsb = s3(qsb + 2);   // (kb+1)*8 % 3
    }

    // ---- epilogue: out = residual(Q) + O / l ----
    __syncthreads();
    if (lane < 32 && ksub == 0) alf[qh * 32 + l31] = 1.0f / l_run;
    __syncthreads();
    #pragma unroll
    for (int r = 0; r < 16; ++r) {
        const int qr = qh * 32 + (r & 3) + 8 * (r >> 2) + 4 * hi;
        const float il = alf[qr];
        const size_t rowoff = (size_t)(q0 + qr) * DIM;
        #pragma unroll
        for (int band = 0; band < NBAND; ++band) {
            const int dcol = band * 128 + ksub * 32 + l31;
            Og[rowoff + dcol] = Qg[rowoff + dcol] + O[band][r] * il;
        }
    }
    #undef QK_MMA
    #undef PV_MMA
    #undef QK_PHASE
    #undef PV_PHASE
}

// ============ fallback (round-2 kernel, verbatim — used if ws too small) ============
#define NDC   8

__global__ __launch_bounds__(512, 2)
void coattn_fb(const float* __restrict__ Sp, const float* __restrict__ Dp,
               float* __restrict__ outp)
{
    const int s   = blockIdx.x;
    const int g   = (s & 7) | ((s >> 8) << 3);
    const int qb  = (s >> 3) & 31;
    const int dir = g >> 3;
    const int b   = g & 7;

    const float* Qg = (dir ? Sp : Dp) + (size_t)b * LSEQ * DIM;
    const float* Kg = (dir ? Dp : Sp) + (size_t)b * LSEQ * DIM;
    float* Og = outp + (size_t)dir * ((size_t)B_ * LSEQ * DIM) + (size_t)b * LSEQ * DIM;
    const int q0 = qb * QBLK;

    __shared__ unsigned short Klds[KBLK * 128];
    __shared__ unsigned short Qlds[QBLK * 128];
    __shared__ unsigned short Plds[QBLK * KBLK];
    __shared__ unsigned short Vlds[128 * KBLK];
    __shared__ float redmax[2][4][32];
    __shared__ float redsum[2][4][32];
    __shared__ float alf[QBLK];

    const int t    = threadIdx.x;
    const int lane = t & 63;
    const int w    = t >> 6;
    const int l31  = lane & 31;
    const int hi   = lane >> 5;
    const int ksub = w & 3;
    const int qh   = w >> 2;

    f32x16 O[NBAND];
    #pragma unroll
    for (int i = 0; i < NBAND; ++i)
        #pragma unroll
        for (int r = 0; r < 16; ++r) O[i][r] = 0.0f;

    float m_run = -INFINITY, l_run = 0.0f;

    const int srow = t >> 4;
    const int fcol = (t & 15) << 2;
    const int vmm  = t & 31;
    const int vkp0 = t >> 5;

    const int krow = ksub * 32 + l31;
    const int qrow = qh * 32 + l31;

    for (int kb = 0; kb < NKB; ++kb) {
        const int k0g = kb * KBLK;
        f32x16 C;
        #pragma unroll
        for (int r = 0; r < 16; ++r) C[r] = 0.0f;

        float4 kreg[8], qreg[4];
        #pragma unroll
        for (int pass = 0; pass < 4; ++pass)
            #pragma unroll
            for (int h = 0; h < 2; ++h)
                kreg[pass * 2 + h] = *(const float4*)(Kg + (size_t)(k0g + pass * 32 + srow) * DIM + fcol + h * 64);
        #pragma unroll
        for (int pass = 0; pass < 2; ++pass)
            #pragma unroll
            for (int h = 0; h < 2; ++h)
                qreg[pass * 2 + h] = *(const float4*)(Qg + (size_t)(q0 + pass * 32 + srow) * DIM + fcol + h * 64);

        #pragma unroll 1
        for (int dc = 0; dc < NDC; ++dc) {
            __syncthreads();
            #pragma unroll
            for (int pass = 0; pass < 4; ++pass)
                #pragma unroll
                for (int h = 0; h < 2; ++h) {
                    const int row = pass * 32 + srow;
                    const int d   = fcol + h * 64;
                    const float4 v = kreg[pass * 2 + h];
                    *(uint2*)&Klds[row * 128 + (d ^ ((row & 7) << 3))] =
                        make_uint2(pk2(v.x, v.y), pk2(v.z, v.w));
                }
            #pragma unroll
            for (int pass = 0; pass < 2; ++pass)
                #pragma unroll
                for (int h = 0; h < 2; ++h) {
                    const int row = pass * 32 + srow;
                    const int d   = fcol + h * 64;
                    const float4 v = qreg[pass * 2 + h];
                    *(uint2*)&Qlds[row * 128 + (d ^ ((row & 7) << 3))] =
                        make_uint2(pk2(v.x, v.y), pk2(v.z, v.w));
                }
            __syncthreads();
            if (dc + 1 < NDC) {
                const int dbase = (dc + 1) * 128;
                #pragma unroll
                for (int pass = 0; pass < 4; ++pass)
                    #pragma unroll
                    for (int h = 0; h < 2; ++h)
                        kreg[pass * 2 + h] = *(const float4*)(Kg + (size_t)(k0g + pass * 32 + srow) * DIM + dbase + fcol + h * 64);
                #pragma unroll
                for (int pass = 0; pass < 2; ++pass)
                    #pragma unroll
                    for (int h = 0; h < 2; ++h)
                        qreg[pass * 2 + h] = *(const float4*)(Qg + (size_t)(q0 + pass * 32 + srow) * DIM + dbase + fcol + h * 64);
            }
            #pragma unroll
            for (int kc = 0; kc < 8; ++kc) {
                const int d0 = kc * 16 + hi * 8;
                f16x8 a  = *(const f16x8*)&Klds[krow * 128 + (d0 ^ ((krow & 7) << 3))];
                f16x8 bq = *(const f16x8*)&Qlds[qrow * 128 + (d0 ^ ((qrow & 7) << 3))];
                C = __builtin_amdgcn_mfma_f32_32x32x16_f16(a, bq, C, 0, 0, 0);
            }
        }

        float rm = -INFINITY;
        #pragma unroll
        for (int r = 0; r < 16; ++r) rm = fmaxf(rm, C[r]);
        rm = fmaxf(rm, __shfl_xor(rm, 32));
        if (lane < 32) redmax[qh][ksub][l31] = rm;
        __syncthreads();

        const float bm = fmaxf(fmaxf(redmax[qh][0][l31], redmax[qh][1][l31]),
                               fmaxf(redmax[qh][2][l31], redmax[qh][3][l31]));
        const float mn = fmaxf(m_run, bm);
        const float al = __expf(m_run - mn);
        float p[16];
        float ps = 0.0f;
        #pragma unroll
        for (int r = 0; r < 16; ++r) { p[r] = __expf(C[r] - mn); ps += p[r]; }
        ps += __shfl_xor(ps, 32);
        if (lane < 32) {
            redsum[qh][ksub][l31] = ps;
            if (ksub == 0) alf[qh * 32 + l31] = al;
        }
        {
            #pragma unroll
            for (int rp = 0; rp < 8; ++rp) {
                const int r  = rp * 2;
                const int kk = ksub * 32 + (r & 3) + 8 * (r >> 2) + 4 * hi;
                *(unsigned*)&Plds[qrow * KBLK + (kk ^ ((qrow & 7) << 3))] = pk2(p[r], p[r + 1]);
            }
        }
        __syncthreads();

        const float bs = redsum[qh][0][l31] + redsum[qh][1][l31] +
                         redsum[qh][2][l31] + redsum[qh][3][l31];
        l_run = l_run * al + bs;
        m_run = mn;

        float alr[16];
        #pragma unroll
        for (int r = 0; r < 16; ++r)
            alr[r] = alf[qh * 32 + (r & 3) + 8 * (r >> 2) + 4 * hi];
        #pragma unroll
        for (int i = 0; i < NBAND; ++i)
            #pragma unroll
            for (int r = 0; r < 16; ++r) O[i][r] *= alr[r];

        f16x8 pa[8];
        #pragma unroll
        for (int kc = 0; kc < 8; ++kc) {
            const int kk0 = kc * 16 + hi * 8;
            pa[kc] = *(const f16x8*)&Plds[qrow * KBLK + (kk0 ^ ((qrow & 7) << 3))];
        }

        float4 v0s[4], v1s[4];
        #pragma unroll
        for (int pass = 0; pass < 4; ++pass) {
            const int kp = pass * 16 + vkp0;
            v0s[pass] = *(const float4*)(Kg + (size_t)(k0g + 2 * kp) * DIM + vmm * 4);
            v1s[pass] = *(const float4*)(Kg + (size_t)(k0g + 2 * kp + 1) * DIM + vmm * 4);
        }

        #pragma unroll
        for (int band = 0; band < NBAND; ++band) {
            __syncthreads();
            #pragma unroll
            for (int pass = 0; pass < 4; ++pass) {
                const int kp = pass * 16 + vkp0;
                const float* a0 = (const float*)&v0s[pass];
                const float* a1 = (const float*)&v1s[pass];
                #pragma unroll
                for (int j = 0; j < 4; ++j) {
                    const int dclw = vmm * 4 + j;
                    *(unsigned*)&Vlds[dclw * KBLK + ((2 * kp) ^ ((dclw & 7) << 3))] = pk2(a0[j], a1[j]);
                }
            }
            __syncthreads();
            if (band + 1 < NBAND) {
                const int cb = (band + 1) * 128;
                #pragma unroll
                for (int pass = 0; pass < 4; ++pass) {
                    const int kp = pass * 16 + vkp0;
                    v0s[pass] = *(const float4*)(Kg + (size_t)(k0g + 2 * kp) * DIM + cb + vmm * 4);
                    v1s[pass] = *(const float4*)(Kg + (size_t)(k0g + 2 * kp + 1) * DIM + cb + vmm * 4);
                }
            }
            const int dclr = ksub * 32 + l31;
            const int sw  = (dclr & 7) << 3;
            #pragma unroll
            for (int kc = 0; kc < 8; ++kc) {
                const int kk0 = kc * 16 + hi * 8;
                f16x8 vb = *(const f16x8*)&Vlds[dclr * KBLK + (kk0 ^ sw)];
                O[band] = __builtin_amdgcn_mfma_f32_32x32x16_f16(pa[kc], vb, O[band], 0, 0, 0);
            }
        }
    }

    if (lane < 32 && ksub == 0) alf[qh * 32 + l31] = 1.0f / l_run;
    __syncthreads();
    #pragma unroll
    for (int r = 0; r < 16; ++r) {
        const int qr = qh * 32 + (r & 3) + 8 * (r >> 2) + 4 * hi;
        const float il = alf[qr];
        const size_t rowoff = (size_t)(q0 + qr) * DIM;
        #pragma unroll
        for (int band = 0; band < NBAND; ++band) {
            const int dcol = band * 128 + ksub * 32 + l31;
            Og[rowoff + dcol] = Qg[rowoff + dcol] + O[band][r] * il;
        }
    }
}

extern "C" void kernel_launch(void* const* d_in, const int* in_sizes, int n_in,
                              void* d_out, int out_size, void* d_ws, size_t ws_size,
                              hipStream_t stream) {
    const float* S = (const float*)d_in[0];
    const float* D = (const float*)d_in[1];
    float* out = (float*)d_out;
    if (ws_size >= WS_NEED) {
        unsigned short* Kimg = (unsigned short*)d_ws;
        unsigned short* Vimg = Kimg + KIMG_US;
        prepass<<<dim3(2048, 1, 1), dim3(256, 1, 1), 0, stream>>>(S, D, Kimg, Vimg);
        coattn_main<<<dim3(512, 1, 1), dim3(512, 1, 1), 0, stream>>>(S, D, out, Kimg, Vimg);
    } else {
        coattn_fb<<<dim3(512, 1, 1), dim3(512, 1, 1), 0, stream>>>(S, D, out);
    }
}